// Round 1
// baseline (1840.350 us; speedup 1.0000x reference)
//
#include <hip/hip_runtime.h>
#include <stdint.h>

// ---- problem constants ----
#define WIN_N 49
#define NH 16
#define HD 32
#define CDIM 512
#define NB 4096
#define M_ROWS (NB * WIN_N)        // 200704 = 128 * 1568 exactly
#define QKV_N 1536
#define SCALE_Q 0.17677669529663689f  // 32^-0.5

typedef __attribute__((ext_vector_type(8))) short bf16x8;
typedef __attribute__((ext_vector_type(4))) float f32x4;

__device__ __forceinline__ unsigned short f2bf(float f) {
  unsigned int u = __float_as_uint(f);
  u += 0x7fff + ((u >> 16) & 1);   // RNE
  return (unsigned short)(u >> 16);
}
__device__ __forceinline__ unsigned int pack2(float a, float b) {
  return (unsigned int)f2bf(a) | ((unsigned int)f2bf(b) << 16);
}

// global->LDS direct DMA, 16B/lane. LDS dest is wave-uniform base + lane*16
// (m97/m104 semantics); global src is per-lane.
typedef const __attribute__((address_space(1))) unsigned int* gas1_t;
typedef __attribute__((address_space(3))) unsigned int* las3_t;
#define GL2LDS(g, l) __builtin_amdgcn_global_load_lds((gas1_t)(g), (las3_t)(l), 16, 0, 0)

// ---- kernel 1: transpose + bf16-convert weights: wT[n][k] = w[k][n] ----
__global__ void prep_weights(const float* __restrict__ qkv_w,
                             const float* __restrict__ proj_w,
                             unsigned short* __restrict__ wqkv_t,
                             unsigned short* __restrict__ wproj_t) {
  int i = blockIdx.x * blockDim.x + threadIdx.x;
  if (i < QKV_N * CDIM) {                 // 786432: [1536][512]
    int n = i >> 9, k = i & 511;
    wqkv_t[i] = f2bf(qkv_w[k * QKV_N + n]);
  } else {
    int j = i - QKV_N * CDIM;
    if (j < CDIM * CDIM) {                // 262144: [512][512]
      int n = j >> 9, k = j & 511;
      wproj_t[j] = f2bf(proj_w[k * CDIM + n]);
    }
  }
}

// ---- kernel 1b: x (f32) -> xb (bf16), one pass, memory-bound ----
// xb lives in d_out (411 MB f32 buffer; xb needs 205 MB; d_out is not written
// until the proj GEMM, by which time xb is dead).
__global__ void conv_x(const float* __restrict__ x,
                       unsigned short* __restrict__ xb, int n8) {
  int i = blockIdx.x * blockDim.x + threadIdx.x;
  const int stride = gridDim.x * blockDim.x;
  for (; i < n8; i += stride) {
    const float4* p = (const float4*)(x + (size_t)i * 8);
    float4 a = p[0], b = p[1];
    *(uint4*)(xb + (size_t)i * 8) =
        make_uint4(pack2(a.x, a.y), pack2(a.z, a.w), pack2(b.x, b.y), pack2(b.z, b.w));
  }
}

// ---- kernel 2/4: C[M][N] = A[M][K] * Bt[N][K]^T, 128x128 tile, BK=32 ----
// m97 structure: global_load_lds width-16 staging (no VGPR round-trip, no
// ds_write), 4 waves in 2x2, each wave 4x4 grid of 16x16x32 bf16 MFMAs.
// Staging layout check: thread tid writes As row r0=tid>>2, col c0=(tid&3)*8
// -> byte offset wid*1024 + lane*16, exactly the HW's uniform-base+lane*16.
template <bool OUT_F32>
__global__ __launch_bounds__(256) void gemm_bt(
    const unsigned short* __restrict__ A, int lda,
    const unsigned short* __restrict__ Bt,
    void* __restrict__ Cptr, int ldc,
    const float* __restrict__ bias,
    int K, int scale_cols, float scale) {
  __shared__ __align__(16) unsigned short As[128 * 32];
  __shared__ __align__(16) unsigned short Bs[128 * 32];
  const int tid = threadIdx.x;
  const int bm = blockIdx.y * 128;
  const int bn = blockIdx.x * 128;
  const int lane = tid & 63, wid = tid >> 6;
  const int wm = (wid & 1) * 64, wn = (wid >> 1) * 64;
  const int quad = lane >> 4, l16 = lane & 15;
  const int r0 = tid >> 2;          // staging row 0..63 (and +64)
  const int c0 = (tid & 3) * 8;     // staging col {0,8,16,24}

  unsigned short* AsW = As + wid * 512;   // wave-uniform LDS dest bases
  unsigned short* BsW = Bs + wid * 512;

  const f32x4 fzero = {0.f, 0.f, 0.f, 0.f};
  f32x4 acc[4][4];
#pragma unroll
  for (int i = 0; i < 4; i++)
#pragma unroll
    for (int j = 0; j < 4; j++) acc[i][j] = fzero;

  const unsigned short* pA = A + (size_t)(bm + r0) * lda + c0;
  const unsigned short* pB = Bt + (size_t)(bn + r0) * K + c0;
  const size_t a64 = (size_t)64 * lda;
  const size_t b64 = (size_t)64 * K;

  for (int kk = 0; kk < K; kk += 32) {
    GL2LDS(pA + kk, AsW);
    GL2LDS(pA + kk + a64, AsW + 2048);
    GL2LDS(pB + kk, BsW);
    GL2LDS(pB + kk + b64, BsW + 2048);
    __syncthreads();   // compiler emits s_waitcnt vmcnt(0) before s_barrier
    bf16x8 a[4], b[4];
#pragma unroll
    for (int i = 0; i < 4; i++) a[i] = *(const bf16x8*)&As[(wm + i * 16 + l16) * 32 + quad * 8];
#pragma unroll
    for (int i = 0; i < 4; i++) b[i] = *(const bf16x8*)&Bs[(wn + i * 16 + l16) * 32 + quad * 8];
#pragma unroll
    for (int i = 0; i < 4; i++)
#pragma unroll
      for (int j = 0; j < 4; j++)
        acc[i][j] = __builtin_amdgcn_mfma_f32_16x16x32_bf16(a[i], b[j], acc[i][j], 0, 0, 0);
    __syncthreads();
  }

  // epilogue: D row = quad*4+reg, col = lane&15 (m89/m91 verified)
#pragma unroll
  for (int i = 0; i < 4; i++) {
    const int row = bm + wm + i * 16 + quad * 4;
#pragma unroll
    for (int j = 0; j < 4; j++) {
      const int col = bn + wn + j * 16 + l16;
      const float bv = bias[col];
      const float sc = (col < scale_cols) ? scale : 1.0f;
#pragma unroll
      for (int r = 0; r < 4; r++) {
        float v = (acc[i][j][r] + bv) * sc;
        if constexpr (OUT_F32)
          ((float*)Cptr)[(size_t)(row + r) * ldc + col] = v;
        else
          ((unsigned short*)Cptr)[(size_t)(row + r) * ldc + col] = f2bf(v);
      }
    }
  }
}

// ---- kernel 3: fused window attention, one wave per (window, head) ----
// qkv layout: [M_ROWS][1536] bf16; cols 0..511=Q*scale (head-major), 512..1023=K, 1024..1535=V.
// Output O overwrites this head's Q columns (disjoint across heads -> race-free).
__global__ __launch_bounds__(256) void attn_mfma(
    unsigned short* __restrict__ qkv,
    const float* __restrict__ bias_table,   // [169][16]
    const float* __restrict__ mask) {       // [64][49][49]
  const int PS = 72;  // P row stride (elems): 16B-aligned rows, good bank spread
  const int VS = 64;  // Vt row stride
  __shared__ __align__(16) unsigned short Pl_all[4][64 * 72];  // 36864 B
  __shared__ __align__(16) unsigned short Vt_all[4][32 * 64];  // 16384 B
  const int tid = threadIdx.x;
  const int wid = tid >> 6, lane = tid & 63;
  const int quad = lane >> 4, l16 = lane & 15;
  const int b = blockIdx.x;
  const int h = blockIdx.y * 4 + wid;
  unsigned short* Pl = Pl_all[wid];
  unsigned short* Vt = Vt_all[wid];
  const size_t row0 = (size_t)b * WIN_N;

  // Q (A-operand) and K (B-operand) fragments direct from global:
  // frag element k-dim = quad*8+j is contiguous 16B in memory.
  bf16x8 aq[4], bk[4];
#pragma unroll
  for (int i = 0; i < 4; i++) {
    size_t r = row0 + i * 16 + l16;
    if (r > (size_t)(M_ROWS - 1)) r = M_ROWS - 1;  // clamp: garbage rows only feed t>=49 / m>=49
    const unsigned short* pq = qkv + r * QKV_N + h * HD + quad * 8;
    aq[i] = *(const bf16x8*)pq;
    bk[i] = *(const bf16x8*)(pq + 512);
  }

  // V^T into LDS: Vt[d][m]; zero the m>=49 pad (0 * garbage would NaN otherwise)
  {
    const int m = lane;
    if (m < WIN_N) {
      const unsigned short* pv = qkv + (row0 + m) * QKV_N + 1024 + h * HD;
      uint4 tv[4];
      tv[0] = *(const uint4*)(pv + 0);
      tv[1] = *(const uint4*)(pv + 8);
      tv[2] = *(const uint4*)(pv + 16);
      tv[3] = *(const uint4*)(pv + 24);
      const unsigned short* tmp = (const unsigned short*)tv;
#pragma unroll
      for (int d = 0; d < 32; d++) Vt[d * VS + m] = tmp[d];
    } else {
#pragma unroll
      for (int d = 0; d < 32; d++) Vt[d * VS + m] = 0;
    }
  }

  // S = (Q*scale) K^T : 16 MFMAs
  const f32x4 fzero = {0.f, 0.f, 0.f, 0.f};
  f32x4 s[4][4];
#pragma unroll
  for (int i = 0; i < 4; i++)
#pragma unroll
    for (int j = 0; j < 4; j++)
      s[i][j] = __builtin_amdgcn_mfma_f32_16x16x32_bf16(aq[i], bk[j], fzero, 0, 0, 0);

  // bias + mask + row softmax (rows live on 16 lanes sharing quad; shfl-xor 1/2/4/8)
  const float* mrow = mask + (size_t)(b & 63) * (WIN_N * WIN_N);
#pragma unroll
  for (int i = 0; i < 4; i++) {
#pragma unroll
    for (int r = 0; r < 4; r++) {
      const int t = i * 16 + quad * 4 + r;
      const int ti = t / 7, tj = t % 7;
      float v[4];
#pragma unroll
      for (int j = 0; j < 4; j++) {
        const int m = j * 16 + l16;
        float x = s[i][j][r];
        if (t < WIN_N && m < WIN_N) {
          const int mi = m / 7, mj = m % 7;
          const int idx = (tj - mj + 6) * 13 + (ti - mi + 6);
          x += bias_table[idx * NH + h] + mrow[t * WIN_N + m];
        }
        if (m >= WIN_N) x = -3.0e38f;  // pad cols vanish in softmax
        v[j] = x;
      }
      float mx = fmaxf(fmaxf(v[0], v[1]), fmaxf(v[2], v[3]));
      mx = fmaxf(mx, __shfl_xor(mx, 1));
      mx = fmaxf(mx, __shfl_xor(mx, 2));
      mx = fmaxf(mx, __shfl_xor(mx, 4));
      mx = fmaxf(mx, __shfl_xor(mx, 8));
      float p[4];
      float sum = 0.f;
#pragma unroll
      for (int j = 0; j < 4; j++) {
        p[j] = __expf(v[j] - mx);
        sum += p[j];
      }
      sum += __shfl_xor(sum, 1);
      sum += __shfl_xor(sum, 2);
      sum += __shfl_xor(sum, 4);
      sum += __shfl_xor(sum, 8);
      const float inv = 1.0f / sum;
#pragma unroll
      for (int j = 0; j < 4; j++) Pl[t * PS + j * 16 + l16] = f2bf(p[j] * inv);
    }
  }
  __syncthreads();  // P,Vt (per-wave regions) ordered before frag reads

  // O = P V : P re-read in A-layout from LDS, Vt is the B^T operand
  f32x4 o[4][2];
#pragma unroll
  for (int i = 0; i < 4; i++)
#pragma unroll
    for (int ni = 0; ni < 2; ni++) o[i][ni] = fzero;
#pragma unroll
  for (int ki = 0; ki < 2; ki++) {
    bf16x8 bv[2];
#pragma unroll
    for (int ni = 0; ni < 2; ni++)
      bv[ni] = *(const bf16x8*)&Vt[(ni * 16 + l16) * VS + ki * 32 + quad * 8];
#pragma unroll
    for (int i = 0; i < 4; i++) {
      bf16x8 ap = *(const bf16x8*)&Pl[(i * 16 + l16) * PS + ki * 32 + quad * 8];
#pragma unroll
      for (int ni = 0; ni < 2; ni++)
        o[i][ni] = __builtin_amdgcn_mfma_f32_16x16x32_bf16(ap, bv[ni], o[i][ni], 0, 0, 0);
    }
  }

  // store O into this head's Q columns (bf16), rows t<49 only
#pragma unroll
  for (int i = 0; i < 4; i++) {
#pragma unroll
    for (int r = 0; r < 4; r++) {
      const int t = i * 16 + quad * 4 + r;
      if (t < WIN_N) {
        unsigned short* po = qkv + (row0 + t) * QKV_N + h * HD;
        po[l16] = f2bf(o[i][0][r]);
        po[16 + l16] = f2bf(o[i][1][r]);
      }
    }
  }
}

extern "C" void kernel_launch(void* const* d_in, const int* in_sizes, int n_in,
                              void* d_out, int out_size, void* d_ws, size_t ws_size,
                              hipStream_t stream) {
  const float* x = (const float*)d_in[0];
  const float* mask = (const float*)d_in[1];
  const float* qkv_w = (const float*)d_in[2];
  const float* qkv_b = (const float*)d_in[3];
  const float* proj_w = (const float*)d_in[4];
  const float* proj_b = (const float*)d_in[5];
  const float* bias_table = (const float*)d_in[6];
  float* out = (float*)d_out;

  // workspace: qkv buffer (bf16, doubles as attention output in Q slots) + transposed weights
  unsigned short* qkvb = (unsigned short*)d_ws;                       // 200704*1536*2 = 616562688 B
  unsigned short* wqkv_t = qkvb + (size_t)M_ROWS * QKV_N;             // 1536*512*2
  unsigned short* wproj_t = wqkv_t + (size_t)QKV_N * CDIM;            // 512*512*2  (total ~619 MB)

  // x_bf16 scratch lives in d_out (dead by the time proj writes out)
  unsigned short* xb = (unsigned short*)d_out;

  prep_weights<<<4096, 256, 0, stream>>>(qkv_w, proj_w, wqkv_t, wproj_t);
  conv_x<<<2048, 256, 0, stream>>>(x, xb, (M_ROWS * CDIM) / 8);

  // QKV: [200704x512]bf16 @ [512x1536] -> bf16, scale Q cols, +qkv_b
  gemm_bt<false><<<dim3(QKV_N / 128, M_ROWS / 128), 256, 0, stream>>>(
      xb, CDIM, wqkv_t, qkvb, QKV_N, qkv_b, CDIM, 512, SCALE_Q);

  // fused window attention
  attn_mfma<<<dim3(NB, NH / 4), 256, 0, stream>>>(qkvb, bias_table, mask);

  // proj: [200704x512]bf16 (stride 1536) @ [512x512] -> f32 out, +proj_b
  gemm_bt<true><<<dim3(CDIM / 128, M_ROWS / 128), 256, 0, stream>>>(
      qkvb, QKV_N, wproj_t, out, CDIM, proj_b, CDIM, 0, 1.0f);
}

// Round 2
// 1830.965 us; speedup vs baseline: 1.0051x; 1.0051x over previous
//
#include <hip/hip_runtime.h>
#include <stdint.h>

// ---- problem constants ----
#define WIN_N 49
#define NH 16
#define HD 32
#define CDIM 512
#define NB 4096
#define M_ROWS (NB * WIN_N)        // 200704 = 128 * 1568 exactly
#define QKV_N 1536
#define SCALE_Q 0.17677669529663689f  // 32^-0.5

typedef __attribute__((ext_vector_type(8))) short bf16x8;
typedef __attribute__((ext_vector_type(4))) float f32x4;

__device__ __forceinline__ unsigned short f2bf(float f) {
  unsigned int u = __float_as_uint(f);
  u += 0x7fff + ((u >> 16) & 1);   // RNE
  return (unsigned short)(u >> 16);
}
__device__ __forceinline__ unsigned int pack2(float a, float b) {
  return (unsigned int)f2bf(a) | ((unsigned int)f2bf(b) << 16);
}

// global->LDS direct DMA, 16B/lane. LDS dest is wave-uniform base + lane*16
// (m97/m104 semantics); global src is per-lane.
typedef const __attribute__((address_space(1))) unsigned int* gas1_t;
typedef __attribute__((address_space(3))) unsigned int* las3_t;
#define GL2LDS(g, l) __builtin_amdgcn_global_load_lds((gas1_t)(g), (las3_t)(l), 16, 0, 0)

// ---- kernel 1: transpose + bf16-convert weights: wT[n][k] = w[k][n] ----
__global__ void prep_weights(const float* __restrict__ qkv_w,
                             const float* __restrict__ proj_w,
                             unsigned short* __restrict__ wqkv_t,
                             unsigned short* __restrict__ wproj_t) {
  int i = blockIdx.x * blockDim.x + threadIdx.x;
  if (i < QKV_N * CDIM) {                 // 786432: [1536][512]
    int n = i >> 9, k = i & 511;
    wqkv_t[i] = f2bf(qkv_w[k * QKV_N + n]);
  } else {
    int j = i - QKV_N * CDIM;
    if (j < CDIM * CDIM) {                // 262144: [512][512]
      int n = j >> 9, k = j & 511;
      wproj_t[j] = f2bf(proj_w[k * CDIM + n]);
    }
  }
}

// ---- kernel 1b: x (f32) -> xb (bf16), one pass, memory-bound ----
__global__ void conv_x(const float* __restrict__ x,
                       unsigned short* __restrict__ xb, int n8) {
  int i = blockIdx.x * blockDim.x + threadIdx.x;
  const int stride = gridDim.x * blockDim.x;
  for (; i < n8; i += stride) {
    const float4* p = (const float4*)(x + (size_t)i * 8);
    float4 a = p[0], b = p[1];
    *(uint4*)(xb + (size_t)i * 8) =
        make_uint4(pack2(a.x, a.y), pack2(a.z, a.w), pack2(b.x, b.y), pack2(b.z, b.w));
  }
}

// ---- kernel 2/4: C[M][N] = A[M][K] * Bt[N][K]^T, 128x128 tile, BK=32 ----
// T3-minimum structure: double-buffered LDS, STAGE(next) issued BEFORE the
// ds_read+MFMA of the current buffer, ONE __syncthreads per K-step (its
// vmcnt(0) drain lands after the compute phase, so load latency hides under
// MFMAs). Unrolled x2 so buffer indices are compile-time (rule #20).
// Requires K/32 even (both call sites: K=512 -> nt=16).
template <bool OUT_F32>
__global__ __launch_bounds__(256) void gemm_bt(
    const unsigned short* __restrict__ A, int lda,
    const unsigned short* __restrict__ Bt,
    void* __restrict__ Cptr, int ldc,
    const float* __restrict__ bias,
    int K, int scale_cols, float scale) {
  __shared__ __align__(16) unsigned short SB[4][128 * 32];  // As0,Bs0,As1,Bs1 = 32 KB
  const int tid = threadIdx.x;

  // T1: XCD-chunked bijective block swizzle. HW round-robins linear block id
  // across 8 XCDs; remap so each XCD owns a contiguous chunk -> the 12 (or 4)
  // blocks sharing an A row-panel run on one XCD and hit its L2.
  const int gx = gridDim.x;
  const int nwg = gx * gridDim.y;            // 18816 / 6272, both % 8 == 0
  int lin = blockIdx.y * gx + blockIdx.x;
  lin = (lin & 7) * (nwg >> 3) + (lin >> 3); // bijective since nwg % 8 == 0
  const int bm = (lin / gx) * 128;
  const int bn = (lin % gx) * 128;

  const int lane = tid & 63, wid = tid >> 6;
  const int wm = (wid & 1) * 64, wn = (wid >> 1) * 64;
  const int quad = lane >> 4, l16 = lane & 15;
  const int r0 = tid >> 2;          // staging row 0..63 (and +64)
  const int c0 = (tid & 3) * 8;     // staging col {0,8,16,24}

  const f32x4 fzero = {0.f, 0.f, 0.f, 0.f};
  f32x4 acc[4][4];
#pragma unroll
  for (int i = 0; i < 4; i++)
#pragma unroll
    for (int j = 0; j < 4; j++) acc[i][j] = fzero;

  const unsigned short* pA = A + (size_t)(bm + r0) * lda + c0;
  const unsigned short* pB = Bt + (size_t)(bn + r0) * K + c0;
  const size_t a64 = (size_t)64 * lda;
  const size_t b64 = (size_t)64 * K;
  const int woff = wid * 512;  // wave-uniform LDS base (wid*1024 B)

#define STAGE(ab, bb, kk_)                              \
  do {                                                  \
    GL2LDS(pA + (kk_), SB[ab] + woff);                  \
    GL2LDS(pA + (kk_) + a64, SB[ab] + woff + 2048);     \
    GL2LDS(pB + (kk_), SB[bb] + woff);                  \
    GL2LDS(pB + (kk_) + b64, SB[bb] + woff + 2048);     \
  } while (0)

#define COMPUTE(ab, bb)                                                          \
  do {                                                                           \
    bf16x8 a[4], b[4];                                                           \
    _Pragma("unroll") for (int i = 0; i < 4; i++)                                \
        a[i] = *(const bf16x8*)&SB[ab][(wm + i * 16 + l16) * 32 + quad * 8];     \
    _Pragma("unroll") for (int i = 0; i < 4; i++)                                \
        b[i] = *(const bf16x8*)&SB[bb][(wn + i * 16 + l16) * 32 + quad * 8];     \
    _Pragma("unroll") for (int i = 0; i < 4; i++)                                \
        _Pragma("unroll") for (int j = 0; j < 4; j++)                            \
            acc[i][j] = __builtin_amdgcn_mfma_f32_16x16x32_bf16(a[i], b[j],      \
                                                                acc[i][j], 0, 0, 0); \
  } while (0)

  const int nt = K >> 5;  // even by contract
  STAGE(0, 1, 0);
  for (int t = 0; t < nt; t += 2) {
    __syncthreads();                         // drains STAGE(buf0); buf1 reads of prev iter done
    STAGE(2, 3, (t + 1) * 32);               // prefetch odd tile into buf1
    COMPUTE(0, 1);                           // compute even tile kk = t*32
    __syncthreads();                         // drains STAGE(buf1); buf0 reads above done
    if (t + 2 < nt) STAGE(0, 1, (t + 2) * 32);
    COMPUTE(2, 3);                           // compute odd tile kk = (t+1)*32
  }
#undef STAGE
#undef COMPUTE

  if constexpr (OUT_F32) {
    // proj epilogue: direct f32 stores (16 lanes x 4 B = 64 B segments)
#pragma unroll
    for (int i = 0; i < 4; i++) {
      const int row = bm + wm + i * 16 + quad * 4;
#pragma unroll
      for (int j = 0; j < 4; j++) {
        const int col = bn + wn + j * 16 + l16;
        const float bv = bias[col];
#pragma unroll
        for (int r = 0; r < 4; r++)
          ((float*)Cptr)[(size_t)(row + r) * ldc + col] = acc[i][j][r] + bv;
      }
    }
  } else {
    // bf16 epilogue: stage the 128x128 bf16 tile in LDS (exactly 32 KB = SB),
    // then store 256 B-coalesced rows (16 lanes x 16 B contiguous).
    unsigned short* Ct = &SB[0][0];
    __syncthreads();  // all waves done with SB as staging buffers
#pragma unroll
    for (int i = 0; i < 4; i++) {
#pragma unroll
      for (int j = 0; j < 4; j++) {
        const int colg = bn + wn + j * 16 + l16;
        const float bv = bias[colg];
        const float sc = (colg < scale_cols) ? scale : 1.0f;
        const int coll = wn + j * 16 + l16;
#pragma unroll
        for (int r = 0; r < 4; r++) {
          const int rowl = wm + i * 16 + quad * 4 + r;
          Ct[rowl * 128 + coll] = f2bf((acc[i][j][r] + bv) * sc);
        }
      }
    }
    __syncthreads();
#pragma unroll
    for (int tt = 0; tt < 8; tt++) {
      const int row = tt * 16 + (tid >> 4);
      const int ce = (tid & 15) * 8;
      uint4 vv = *(const uint4*)&Ct[row * 128 + ce];
      *(uint4*)&((unsigned short*)Cptr)[(size_t)(bm + row) * ldc + bn + ce] = vv;
    }
  }
}

// ---- kernel 3: fused window attention, one wave per (window, head) ----
// qkv layout: [M_ROWS][1536] bf16; cols 0..511=Q*scale (head-major), 512..1023=K, 1024..1535=V.
// Output O overwrites this head's Q columns (disjoint across heads -> race-free).
__global__ __launch_bounds__(256) void attn_mfma(
    unsigned short* __restrict__ qkv,
    const float* __restrict__ bias_table,   // [169][16]
    const float* __restrict__ mask) {       // [64][49][49]
  const int PS = 72;  // P row stride (elems): 16B-aligned rows, good bank spread
  const int VS = 64;  // Vt row stride
  __shared__ __align__(16) unsigned short Pl_all[4][64 * 72];  // 36864 B
  __shared__ __align__(16) unsigned short Vt_all[4][32 * 64];  // 16384 B
  const int tid = threadIdx.x;
  const int wid = tid >> 6, lane = tid & 63;
  const int quad = lane >> 4, l16 = lane & 15;
  const int b = blockIdx.x;
  const int h = blockIdx.y * 4 + wid;
  unsigned short* Pl = Pl_all[wid];
  unsigned short* Vt = Vt_all[wid];
  const size_t row0 = (size_t)b * WIN_N;

  // Q (A-operand) and K (B-operand) fragments direct from global:
  // frag element k-dim = quad*8+j is contiguous 16B in memory.
  bf16x8 aq[4], bk[4];
#pragma unroll
  for (int i = 0; i < 4; i++) {
    size_t r = row0 + i * 16 + l16;
    if (r > (size_t)(M_ROWS - 1)) r = M_ROWS - 1;  // clamp: garbage rows only feed t>=49 / m>=49
    const unsigned short* pq = qkv + r * QKV_N + h * HD + quad * 8;
    aq[i] = *(const bf16x8*)pq;
    bk[i] = *(const bf16x8*)(pq + 512);
  }

  // V^T into LDS: Vt[d][m]; zero the m>=49 pad (0 * garbage would NaN otherwise)
  {
    const int m = lane;
    if (m < WIN_N) {
      const unsigned short* pv = qkv + (row0 + m) * QKV_N + 1024 + h * HD;
      uint4 tv[4];
      tv[0] = *(const uint4*)(pv + 0);
      tv[1] = *(const uint4*)(pv + 8);
      tv[2] = *(const uint4*)(pv + 16);
      tv[3] = *(const uint4*)(pv + 24);
      const unsigned short* tmp = (const unsigned short*)tv;
#pragma unroll
      for (int d = 0; d < 32; d++) Vt[d * VS + m] = tmp[d];
    } else {
#pragma unroll
      for (int d = 0; d < 32; d++) Vt[d * VS + m] = 0;
    }
  }

  // S = (Q*scale) K^T : 16 MFMAs
  const f32x4 fzero = {0.f, 0.f, 0.f, 0.f};
  f32x4 s[4][4];
#pragma unroll
  for (int i = 0; i < 4; i++)
#pragma unroll
    for (int j = 0; j < 4; j++)
      s[i][j] = __builtin_amdgcn_mfma_f32_16x16x32_bf16(aq[i], bk[j], fzero, 0, 0, 0);

  // bias + mask + row softmax (rows live on 16 lanes sharing quad; shfl-xor 1/2/4/8)
  const float* mrow = mask + (size_t)(b & 63) * (WIN_N * WIN_N);
#pragma unroll
  for (int i = 0; i < 4; i++) {
#pragma unroll
    for (int r = 0; r < 4; r++) {
      const int t = i * 16 + quad * 4 + r;
      const int ti = t / 7, tj = t % 7;
      float v[4];
#pragma unroll
      for (int j = 0; j < 4; j++) {
        const int m = j * 16 + l16;
        float x = s[i][j][r];
        if (t < WIN_N && m < WIN_N) {
          const int mi = m / 7, mj = m % 7;
          const int idx = (tj - mj + 6) * 13 + (ti - mi + 6);
          x += bias_table[idx * NH + h] + mrow[t * WIN_N + m];
        }
        if (m >= WIN_N) x = -3.0e38f;  // pad cols vanish in softmax
        v[j] = x;
      }
      float mx = fmaxf(fmaxf(v[0], v[1]), fmaxf(v[2], v[3]));
      mx = fmaxf(mx, __shfl_xor(mx, 1));
      mx = fmaxf(mx, __shfl_xor(mx, 2));
      mx = fmaxf(mx, __shfl_xor(mx, 4));
      mx = fmaxf(mx, __shfl_xor(mx, 8));
      float p[4];
      float sum = 0.f;
#pragma unroll
      for (int j = 0; j < 4; j++) {
        p[j] = __expf(v[j] - mx);
        sum += p[j];
      }
      sum += __shfl_xor(sum, 1);
      sum += __shfl_xor(sum, 2);
      sum += __shfl_xor(sum, 4);
      sum += __shfl_xor(sum, 8);
      const float inv = 1.0f / sum;
#pragma unroll
      for (int j = 0; j < 4; j++) Pl[t * PS + j * 16 + l16] = f2bf(p[j] * inv);
    }
  }
  __syncthreads();  // P,Vt (per-wave regions) ordered before frag reads

  // O = P V : P re-read in A-layout from LDS, Vt is the B^T operand
  f32x4 o[4][2];
#pragma unroll
  for (int i = 0; i < 4; i++)
#pragma unroll
    for (int ni = 0; ni < 2; ni++) o[i][ni] = fzero;
#pragma unroll
  for (int ki = 0; ki < 2; ki++) {
    bf16x8 bv[2];
#pragma unroll
    for (int ni = 0; ni < 2; ni++)
      bv[ni] = *(const bf16x8*)&Vt[(ni * 16 + l16) * VS + ki * 32 + quad * 8];
#pragma unroll
    for (int i = 0; i < 4; i++) {
      bf16x8 ap = *(const bf16x8*)&Pl[(i * 16 + l16) * PS + ki * 32 + quad * 8];
#pragma unroll
      for (int ni = 0; ni < 2; ni++)
        o[i][ni] = __builtin_amdgcn_mfma_f32_16x16x32_bf16(ap, bv[ni], o[i][ni], 0, 0, 0);
    }
  }

  // store O into this head's Q columns (bf16), rows t<49 only
#pragma unroll
  for (int i = 0; i < 4; i++) {
#pragma unroll
    for (int r = 0; r < 4; r++) {
      const int t = i * 16 + quad * 4 + r;
      if (t < WIN_N) {
        unsigned short* po = qkv + (row0 + t) * QKV_N + h * HD;
        po[l16] = f2bf(o[i][0][r]);
        po[16 + l16] = f2bf(o[i][1][r]);
      }
    }
  }
}

extern "C" void kernel_launch(void* const* d_in, const int* in_sizes, int n_in,
                              void* d_out, int out_size, void* d_ws, size_t ws_size,
                              hipStream_t stream) {
  const float* x = (const float*)d_in[0];
  const float* mask = (const float*)d_in[1];
  const float* qkv_w = (const float*)d_in[2];
  const float* qkv_b = (const float*)d_in[3];
  const float* proj_w = (const float*)d_in[4];
  const float* proj_b = (const float*)d_in[5];
  const float* bias_table = (const float*)d_in[6];
  float* out = (float*)d_out;

  // workspace: qkv buffer (bf16, doubles as attention output in Q slots) + transposed weights
  unsigned short* qkvb = (unsigned short*)d_ws;                       // 200704*1536*2 = 616562688 B
  unsigned short* wqkv_t = qkvb + (size_t)M_ROWS * QKV_N;             // 1536*512*2
  unsigned short* wproj_t = wqkv_t + (size_t)QKV_N * CDIM;            // 512*512*2  (total ~619 MB)

  // x_bf16 scratch lives in d_out (dead by the time proj writes out)
  unsigned short* xb = (unsigned short*)d_out;

  prep_weights<<<4096, 256, 0, stream>>>(qkv_w, proj_w, wqkv_t, wproj_t);
  conv_x<<<2048, 256, 0, stream>>>(x, xb, (M_ROWS * CDIM) / 8);

  // QKV: [200704x512]bf16 @ [512x1536] -> bf16, scale Q cols, +qkv_b
  gemm_bt<false><<<dim3(QKV_N / 128, M_ROWS / 128), 256, 0, stream>>>(
      xb, CDIM, wqkv_t, qkvb, QKV_N, qkv_b, CDIM, 512, SCALE_Q);

  // fused window attention
  attn_mfma<<<dim3(NB, NH / 4), 256, 0, stream>>>(qkvb, bias_table, mask);

  // proj: [200704x512]bf16 (stride 1536) @ [512x512] -> f32 out, +proj_b
  gemm_bt<true><<<dim3(CDIM / 128, M_ROWS / 128), 256, 0, stream>>>(
      qkvb, QKV_N, wproj_t, out, CDIM, proj_b, CDIM, 0, 1.0f);
}